// Round 1
// baseline (1205.105 us; speedup 1.0000x reference)
//
#include <hip/hip_runtime.h>
#include <cmath>

#define NN 50000
#define NE 600000
#define NF 128
#define NH 64
#define NC 40

// ---------------- proj1: p1[n,o] = sum_k x[n,k] * Wl1[o,k]  (o<64, k<128) ----
__global__ __launch_bounds__(256) void k_proj128to64(
    const float* __restrict__ X, const float* __restrict__ W,  // W [64,128]
    float* __restrict__ P) {
  __shared__ float wt[NF * NH];  // wt[k*64+o] = W[o*128+k]
  int tid = threadIdx.x;
  for (int i = tid; i < NF * NH; i += 256) {
    int o = i >> 7, k = i & 127;
    wt[k * NH + o] = W[i];
  }
  __syncthreads();
  int lane = tid & 63;
  int wave = blockIdx.x * 4 + (tid >> 6);
  int wstride = gridDim.x * 4;
  for (int n = wave; n < NN; n += wstride) {
    const float4* xr = (const float4*)(X + (size_t)n * NF);
    float acc = 0.f;
#pragma unroll 8
    for (int kk = 0; kk < 32; ++kk) {
      float4 v = xr[kk];
      const float* w4 = &wt[(kk * 4) * NH + lane];
      acc += v.x * w4[0] + v.y * w4[NH] + v.z * w4[2 * NH] + v.w * w4[3 * NH];
    }
    P[(size_t)n * NH + lane] = acc;
  }
}

// ---------------- scatter64: agg[dst] += p1[src] (64 feats) + degree count ---
__global__ __launch_bounds__(256) void k_scatter64(
    const float* __restrict__ P, const int* __restrict__ src,
    const int* __restrict__ dst, float* __restrict__ agg,
    float* __restrict__ cnt) {
  long long i0 = (long long)blockIdx.x * blockDim.x + threadIdx.x;
  long long stride = (long long)gridDim.x * blockDim.x;
  const long long total = (long long)NE * 16;
  for (long long i = i0; i < total; i += stride) {
    int e = (int)(i >> 4);
    int c = ((int)i & 15) << 2;
    int s = src[e], d = dst[e];
    float4 v = *(const float4*)(P + (size_t)s * NH + c);
    float* b = agg + (size_t)d * NH + c;
    unsafeAtomicAdd(b + 0, v.x);
    unsafeAtomicAdd(b + 1, v.y);
    unsafeAtomicAdd(b + 2, v.z);
    unsafeAtomicAdd(b + 3, v.w);
    if (c == 0) unsafeAtomicAdd(cnt + d, 1.0f);
  }
}

// ---------------- hcomp: h = sigmoid(agg/cnt + bl1 + x @ Wr1.T) --------------
__global__ __launch_bounds__(256) void k_hcomp(
    const float* __restrict__ X, const float* __restrict__ Wr,
    const float* __restrict__ bl, const float* __restrict__ aggP,
    const float* __restrict__ cnt, float* __restrict__ Hout) {
  __shared__ float wt[NF * NH];
  int tid = threadIdx.x;
  for (int i = tid; i < NF * NH; i += 256) {
    int o = i >> 7, k = i & 127;
    wt[k * NH + o] = Wr[i];
  }
  __syncthreads();
  int lane = tid & 63;
  int wave = blockIdx.x * 4 + (tid >> 6);
  int wstride = gridDim.x * 4;
  for (int n = wave; n < NN; n += wstride) {
    const float4* xr = (const float4*)(X + (size_t)n * NF);
    float acc = 0.f;
#pragma unroll 8
    for (int kk = 0; kk < 32; ++kk) {
      float4 v = xr[kk];
      const float* w4 = &wt[(kk * 4) * NH + lane];
      acc += v.x * w4[0] + v.y * w4[NH] + v.z * w4[2 * NH] + v.w * w4[3 * NH];
    }
    float c = cnt[n];
    float inv = 1.0f / fmaxf(c, 1.0f);
    float val = aggP[(size_t)n * NH + lane] * inv + bl[lane] + acc;
    Hout[(size_t)n * NH + lane] = 1.0f / (1.0f + __expf(-val));
  }
}

// ---------------- proj2: p2[n,j] = sum_k h[n,k] * Wl2[j,k]  (j<40, k<64) -----
__global__ __launch_bounds__(256) void k_proj64to40(
    const float* __restrict__ Hin, const float* __restrict__ W,  // W [40,64]
    float* __restrict__ P2) {
  __shared__ float wt[NH * NC];  // wt[k*40+j] = W[j*64+k]
  int tid = threadIdx.x;
  for (int i = tid; i < NH * NC; i += 256) {
    int j = i >> 6, k = i & 63;
    wt[k * NC + j] = W[i];
  }
  __syncthreads();
  int lane = tid & 63;
  int wave = blockIdx.x * 4 + (tid >> 6);
  int wstride = gridDim.x * 4;
  for (int n = wave; n < NN; n += wstride) {
    if (lane < NC) {
      const float4* hr = (const float4*)(Hin + (size_t)n * NH);
      float acc = 0.f;
#pragma unroll 8
      for (int kk = 0; kk < 16; ++kk) {
        float4 v = hr[kk];
        const float* w4 = &wt[(kk * 4) * NC + lane];
        acc += v.x * w4[0] + v.y * w4[NC] + v.z * w4[2 * NC] + v.w * w4[3 * NC];
      }
      P2[(size_t)n * NC + lane] = acc;
    }
  }
}

// ---------------- scatter40: agg2[dst] += p2[src] (40 feats) -----------------
__global__ __launch_bounds__(256) void k_scatter40(
    const float* __restrict__ P, const int* __restrict__ src,
    const int* __restrict__ dst, float* __restrict__ agg) {
  long long i0 = (long long)blockIdx.x * blockDim.x + threadIdx.x;
  long long stride = (long long)gridDim.x * blockDim.x;
  const long long total = (long long)NE * 10;
  for (long long i = i0; i < total; i += stride) {
    int e = (int)(i / 10);
    int c = ((int)(i % 10)) << 2;
    int s = src[e], d = dst[e];
    float4 v = *(const float4*)(P + (size_t)s * NC + c);
    float* b = agg + (size_t)d * NC + c;
    unsafeAtomicAdd(b + 0, v.x);
    unsafeAtomicAdd(b + 1, v.y);
    unsafeAtomicAdd(b + 2, v.z);
    unsafeAtomicAdd(b + 3, v.w);
  }
}

// ---------------- out: out = agg2/cnt + bl2 + h @ Wr2.T ----------------------
__global__ __launch_bounds__(256) void k_out(
    const float* __restrict__ Hin, const float* __restrict__ W,  // W [40,64]
    const float* __restrict__ bl, const float* __restrict__ aggP2,
    const float* __restrict__ cnt, float* __restrict__ Out) {
  __shared__ float wt[NH * NC];
  int tid = threadIdx.x;
  for (int i = tid; i < NH * NC; i += 256) {
    int j = i >> 6, k = i & 63;
    wt[k * NC + j] = W[i];
  }
  __syncthreads();
  int lane = tid & 63;
  int wave = blockIdx.x * 4 + (tid >> 6);
  int wstride = gridDim.x * 4;
  for (int n = wave; n < NN; n += wstride) {
    if (lane < NC) {
      const float4* hr = (const float4*)(Hin + (size_t)n * NH);
      float acc = 0.f;
#pragma unroll 8
      for (int kk = 0; kk < 16; ++kk) {
        float4 v = hr[kk];
        const float* w4 = &wt[(kk * 4) * NC + lane];
        acc += v.x * w4[0] + v.y * w4[NC] + v.z * w4[2 * NC] + v.w * w4[3 * NC];
      }
      float c = cnt[n];
      float inv = 1.0f / fmaxf(c, 1.0f);
      Out[(size_t)n * NC + lane] =
          aggP2[(size_t)n * NC + lane] * inv + bl[lane] + acc;
    }
  }
}

extern "C" void kernel_launch(void* const* d_in, const int* in_sizes, int n_in,
                              void* d_out, int out_size, void* d_ws,
                              size_t ws_size, hipStream_t stream) {
  const float* x = (const float*)d_in[0];
  const int* ei = (const int*)d_in[1];
  const float* Wl1 = (const float*)d_in[2];
  const float* bl1 = (const float*)d_in[3];
  const float* Wr1 = (const float*)d_in[4];
  const float* Wl2 = (const float*)d_in[5];
  const float* bl2 = (const float*)d_in[6];
  const float* Wr2 = (const float*)d_in[7];
  float* out = (float*)d_out;

  const int* src = ei;        // edge_index[0]
  const int* dst = ei + NE;   // edge_index[1]

  // workspace layout (floats):
  float* p1 = (float*)d_ws;                    // [NN*64]
  float* h = p1 + (size_t)NN * NH;             // [NN*64]
  float* p2 = h + (size_t)NN * NH;             // [NN*40]
  float* aggP1 = p2 + (size_t)NN * NC;         // [NN*64]  (zeroed)
  float* aggP2 = aggP1 + (size_t)NN * NH;      // [NN*40]  (zeroed)
  float* cnt = aggP2 + (size_t)NN * NC;        // [NN]     (zeroed)

  // zero agg buffers + cnt (contiguous tail region)
  hipMemsetAsync(aggP1, 0, ((size_t)NN * (NH + NC) + NN) * sizeof(float),
                 stream);

  k_proj128to64<<<2048, 256, 0, stream>>>(x, Wl1, p1);
  k_scatter64<<<4096, 256, 0, stream>>>(p1, src, dst, aggP1, cnt);
  k_hcomp<<<2048, 256, 0, stream>>>(x, Wr1, bl1, aggP1, cnt, h);
  k_proj64to40<<<2048, 256, 0, stream>>>(h, Wl2, p2);
  k_scatter40<<<4096, 256, 0, stream>>>(p2, src, dst, aggP2);
  k_out<<<2048, 256, 0, stream>>>(h, Wr2, bl2, aggP2, cnt, out);
}

// Round 2
// 528.634 us; speedup vs baseline: 2.2797x; 2.2797x over previous
//
#include <hip/hip_runtime.h>
#include <cmath>

#define NN 50000
#define NE 600000
#define NF 128
#define NH 64
#define NC 40

#define SCAN_TPB 512
#define SCAN_NBLK 98  // 98*512 = 50176 >= 50000

// ---------------- CSR build ----------------
__global__ __launch_bounds__(256) void k_hist(const int* __restrict__ dst,
                                              int* __restrict__ deg) {
  int i0 = blockIdx.x * blockDim.x + threadIdx.x;
  int stride = gridDim.x * blockDim.x;
  for (int e = i0; e < NE; e += stride) atomicAdd(&deg[dst[e]], 1);
}

__global__ __launch_bounds__(SCAN_TPB) void k_scan1(const int* __restrict__ deg,
                                                    int* __restrict__ blocksum) {
  __shared__ int sd[SCAN_TPB];
  int i = blockIdx.x * SCAN_TPB + threadIdx.x;
  sd[threadIdx.x] = (i < NN) ? deg[i] : 0;
  __syncthreads();
  for (int off = SCAN_TPB / 2; off > 0; off >>= 1) {
    if (threadIdx.x < off) sd[threadIdx.x] += sd[threadIdx.x + off];
    __syncthreads();
  }
  if (threadIdx.x == 0) blocksum[blockIdx.x] = sd[0];
}

__global__ __launch_bounds__(128) void k_scan2(const int* __restrict__ blocksum,
                                               int* __restrict__ blockoff) {
  __shared__ int sd[128];
  int tid = threadIdx.x;
  int v = (tid < SCAN_NBLK) ? blocksum[tid] : 0;
  sd[tid] = v;
  __syncthreads();
  for (int off = 1; off < 128; off <<= 1) {
    int t = (tid >= off) ? sd[tid - off] : 0;
    __syncthreads();
    sd[tid] += t;
    __syncthreads();
  }
  if (tid < SCAN_NBLK) blockoff[tid] = sd[tid] - v;  // exclusive
}

__global__ __launch_bounds__(SCAN_TPB) void k_scan3(
    const int* __restrict__ deg, const int* __restrict__ blockoff,
    int* __restrict__ rowptr, int* __restrict__ cursor) {
  __shared__ int sd[SCAN_TPB];
  int tid = threadIdx.x;
  int i = blockIdx.x * SCAN_TPB + tid;
  int v = (i < NN) ? deg[i] : 0;
  sd[tid] = v;
  __syncthreads();
  for (int off = 1; off < SCAN_TPB; off <<= 1) {
    int t = (tid >= off) ? sd[tid - off] : 0;
    __syncthreads();
    sd[tid] += t;
    __syncthreads();
  }
  if (i < NN) {
    int excl = blockoff[blockIdx.x] + sd[tid] - v;
    rowptr[i] = excl;
    cursor[i] = excl;
  }
}

__global__ __launch_bounds__(256) void k_fill(const int* __restrict__ src,
                                              const int* __restrict__ dst,
                                              int* __restrict__ cursor,
                                              int* __restrict__ eid) {
  int i0 = blockIdx.x * blockDim.x + threadIdx.x;
  int stride = gridDim.x * blockDim.x;
  for (int e = i0; e < NE; e += stride) {
    int pos = atomicAdd(&cursor[dst[e]], 1);
    eid[pos] = src[e];
  }
}

// ---------------- proj1: p1[n,o] = sum_k x[n,k] * Wl1[o,k] ----
__global__ __launch_bounds__(256) void k_proj128to64(
    const float* __restrict__ X, const float* __restrict__ W,  // W [64,128]
    float* __restrict__ P) {
  __shared__ float wt[NF * NH];  // wt[k*64+o] = W[o*128+k]
  int tid = threadIdx.x;
  for (int i = tid; i < NF * NH; i += 256) {
    int o = i >> 7, k = i & 127;
    wt[k * NH + o] = W[i];
  }
  __syncthreads();
  int lane = tid & 63;
  int wave = blockIdx.x * 4 + (tid >> 6);
  int wstride = gridDim.x * 4;
  for (int n = wave; n < NN; n += wstride) {
    const float4* xr = (const float4*)(X + (size_t)n * NF);
    float acc = 0.f;
#pragma unroll 8
    for (int kk = 0; kk < 32; ++kk) {
      float4 v = xr[kk];
      const float* w4 = &wt[(kk * 4) * NH + lane];
      acc += v.x * w4[0] + v.y * w4[NH] + v.z * w4[2 * NH] + v.w * w4[3 * NH];
    }
    P[(size_t)n * NH + lane] = acc;
  }
}

// -------- hcomp fused: h = sigmoid(gather_mean(p1) + bl1 + x @ Wr1.T) --------
__global__ __launch_bounds__(256) void k_hcomp_fused(
    const float* __restrict__ X, const float* __restrict__ Wr,
    const float* __restrict__ bl, const float* __restrict__ P,
    const int* __restrict__ rowptr, const int* __restrict__ deg,
    const int* __restrict__ eid, float* __restrict__ Hout) {
  __shared__ float wt[NF * NH];
  int tid = threadIdx.x;
  for (int i = tid; i < NF * NH; i += 256) {
    int o = i >> 7, k = i & 127;
    wt[k * NH + o] = Wr[i];
  }
  __syncthreads();
  int lane = tid & 63;
  int wave = blockIdx.x * 4 + (tid >> 6);
  int wstride = gridDim.x * 4;
  for (int n = wave; n < NN; n += wstride) {
    const float4* xr = (const float4*)(X + (size_t)n * NF);
    float acc = 0.f;
#pragma unroll 8
    for (int kk = 0; kk < 32; ++kk) {
      float4 v = xr[kk];
      const float* w4 = &wt[(kk * 4) * NH + lane];
      acc += v.x * w4[0] + v.y * w4[NH] + v.z * w4[2 * NH] + v.w * w4[3 * NH];
    }
    int r0 = rowptr[n];
    int dg = deg[n];
    float aggv = 0.f;
    int snext = (dg > 0) ? eid[r0] : 0;
    for (int j = 0; j < dg; ++j) {
      int scur = snext;
      if (j + 1 < dg) snext = eid[r0 + j + 1];
      aggv += P[(size_t)scur * NH + lane];
    }
    float inv = 1.0f / (float)((dg > 0) ? dg : 1);
    float val = aggv * inv + bl[lane] + acc;
    Hout[(size_t)n * NH + lane] = 1.0f / (1.0f + __expf(-val));
  }
}

// ---------------- proj2: p2[n,j] = sum_k h[n,k] * Wl2[j,k] ----
__global__ __launch_bounds__(256) void k_proj64to40(
    const float* __restrict__ Hin, const float* __restrict__ W,  // W [40,64]
    float* __restrict__ P2) {
  __shared__ float wt[NH * NC];  // wt[k*40+j] = W[j*64+k]
  int tid = threadIdx.x;
  for (int i = tid; i < NH * NC; i += 256) {
    int j = i >> 6, k = i & 63;
    wt[k * NC + j] = W[i];
  }
  __syncthreads();
  int lane = tid & 63;
  int wave = blockIdx.x * 4 + (tid >> 6);
  int wstride = gridDim.x * 4;
  for (int n = wave; n < NN; n += wstride) {
    if (lane < NC) {
      const float4* hr = (const float4*)(Hin + (size_t)n * NH);
      float acc = 0.f;
#pragma unroll 8
      for (int kk = 0; kk < 16; ++kk) {
        float4 v = hr[kk];
        const float* w4 = &wt[(kk * 4) * NC + lane];
        acc += v.x * w4[0] + v.y * w4[NC] + v.z * w4[2 * NC] + v.w * w4[3 * NC];
      }
      P2[(size_t)n * NC + lane] = acc;
    }
  }
}

// -------- out fused: out = gather_mean(p2) + bl2 + h @ Wr2.T --------
__global__ __launch_bounds__(256) void k_out_fused(
    const float* __restrict__ Hin, const float* __restrict__ W,
    const float* __restrict__ bl, const float* __restrict__ P2,
    const int* __restrict__ rowptr, const int* __restrict__ deg,
    const int* __restrict__ eid, float* __restrict__ Out) {
  __shared__ float wt[NH * NC];
  int tid = threadIdx.x;
  for (int i = tid; i < NH * NC; i += 256) {
    int j = i >> 6, k = i & 63;
    wt[k * NC + j] = W[i];
  }
  __syncthreads();
  int lane = tid & 63;
  int wave = blockIdx.x * 4 + (tid >> 6);
  int wstride = gridDim.x * 4;
  for (int n = wave; n < NN; n += wstride) {
    if (lane < NC) {
      const float4* hr = (const float4*)(Hin + (size_t)n * NH);
      float acc = 0.f;
#pragma unroll 8
      for (int kk = 0; kk < 16; ++kk) {
        float4 v = hr[kk];
        const float* w4 = &wt[(kk * 4) * NC + lane];
        acc += v.x * w4[0] + v.y * w4[NC] + v.z * w4[2 * NC] + v.w * w4[3 * NC];
      }
      int r0 = rowptr[n];
      int dg = deg[n];
      float aggv = 0.f;
      int snext = (dg > 0) ? eid[r0] : 0;
      for (int j = 0; j < dg; ++j) {
        int scur = snext;
        if (j + 1 < dg) snext = eid[r0 + j + 1];
        aggv += P2[(size_t)scur * NC + lane];
      }
      float inv = 1.0f / (float)((dg > 0) ? dg : 1);
      Out[(size_t)n * NC + lane] = aggv * inv + bl[lane] + acc;
    }
  }
}

extern "C" void kernel_launch(void* const* d_in, const int* in_sizes, int n_in,
                              void* d_out, int out_size, void* d_ws,
                              size_t ws_size, hipStream_t stream) {
  const float* x = (const float*)d_in[0];
  const int* ei = (const int*)d_in[1];
  const float* Wl1 = (const float*)d_in[2];
  const float* bl1 = (const float*)d_in[3];
  const float* Wr1 = (const float*)d_in[4];
  const float* Wl2 = (const float*)d_in[5];
  const float* bl2 = (const float*)d_in[6];
  const float* Wr2 = (const float*)d_in[7];
  float* out = (float*)d_out;

  const int* src = ei;       // edge_index[0]
  const int* dst = ei + NE;  // edge_index[1]

  // workspace layout
  float* p1 = (float*)d_ws;                 // [NN*64]
  float* h = p1 + (size_t)NN * NH;          // [NN*64]
  float* p2 = h + (size_t)NN * NH;          // [NN*40]
  int* deg = (int*)(p2 + (size_t)NN * NC);  // [NN]   (zeroed)
  int* rowptr = deg + NN;                   // [NN]
  int* cursor = rowptr + NN;                // [NN]
  int* blocksum = cursor + NN;              // [128]
  int* blockoff = blocksum + 128;           // [128]
  int* eid = blockoff + 128;                // [NE]

  hipMemsetAsync(deg, 0, NN * sizeof(int), stream);

  // CSR build
  k_hist<<<1024, 256, 0, stream>>>(dst, deg);
  k_scan1<<<SCAN_NBLK, SCAN_TPB, 0, stream>>>(deg, blocksum);
  k_scan2<<<1, 128, 0, stream>>>(blocksum, blockoff);
  k_scan3<<<SCAN_NBLK, SCAN_TPB, 0, stream>>>(deg, blockoff, rowptr, cursor);
  k_fill<<<1024, 256, 0, stream>>>(src, dst, cursor, eid);

  // layer 1
  k_proj128to64<<<2048, 256, 0, stream>>>(x, Wl1, p1);
  k_hcomp_fused<<<12500, 256, 0, stream>>>(x, Wr1, bl1, p1, rowptr, deg, eid, h);

  // layer 2
  k_proj64to40<<<12500, 256, 0, stream>>>(h, Wl2, p2);
  k_out_fused<<<12500, 256, 0, stream>>>(h, Wr2, bl2, p2, rowptr, deg, eid, out);
}

// Round 3
// 314.940 us; speedup vs baseline: 3.8265x; 1.6785x over previous
//
#include <hip/hip_runtime.h>
#include <cmath>

#define NN 50000
#define NE 600000
#define NF 128
#define NH 64
#define NC 40

#define SCAN_TPB 512
#define SCAN_NBLK 98  // 98*512 = 50176 >= 50000

#define LDSP1 65  // pad: bank = (k+o)%32 on both stage-write and compute-read
#define LDSP2 41  // pad for layer-2 weights (stride 41, gcd(41%32=9,32)=1)

// ---------------- CSR build ----------------
__global__ __launch_bounds__(256) void k_hist(const int* __restrict__ dst,
                                              int* __restrict__ deg) {
  int i0 = blockIdx.x * blockDim.x + threadIdx.x;
  int stride = gridDim.x * blockDim.x;
  for (int e = i0; e < NE; e += stride) atomicAdd(&deg[dst[e]], 1);
}

__global__ __launch_bounds__(SCAN_TPB) void k_scan1(const int* __restrict__ deg,
                                                    int* __restrict__ blocksum) {
  __shared__ int sd[SCAN_TPB];
  int i = blockIdx.x * SCAN_TPB + threadIdx.x;
  sd[threadIdx.x] = (i < NN) ? deg[i] : 0;
  __syncthreads();
  for (int off = SCAN_TPB / 2; off > 0; off >>= 1) {
    if (threadIdx.x < off) sd[threadIdx.x] += sd[threadIdx.x + off];
    __syncthreads();
  }
  if (threadIdx.x == 0) blocksum[blockIdx.x] = sd[0];
}

__global__ __launch_bounds__(128) void k_scan2(const int* __restrict__ blocksum,
                                               int* __restrict__ blockoff) {
  __shared__ int sd[128];
  int tid = threadIdx.x;
  int v = (tid < SCAN_NBLK) ? blocksum[tid] : 0;
  sd[tid] = v;
  __syncthreads();
  for (int off = 1; off < 128; off <<= 1) {
    int t = (tid >= off) ? sd[tid - off] : 0;
    __syncthreads();
    sd[tid] += t;
    __syncthreads();
  }
  if (tid < SCAN_NBLK) blockoff[tid] = sd[tid] - v;  // exclusive
}

__global__ __launch_bounds__(SCAN_TPB) void k_scan3(
    const int* __restrict__ deg, const int* __restrict__ blockoff,
    int* __restrict__ rowptr, int* __restrict__ cursor) {
  __shared__ int sd[SCAN_TPB];
  int tid = threadIdx.x;
  int i = blockIdx.x * SCAN_TPB + tid;
  int v = (i < NN) ? deg[i] : 0;
  sd[tid] = v;
  __syncthreads();
  for (int off = 1; off < SCAN_TPB; off <<= 1) {
    int t = (tid >= off) ? sd[tid - off] : 0;
    __syncthreads();
    sd[tid] += t;
    __syncthreads();
  }
  if (i < NN) {
    int excl = blockoff[blockIdx.x] + sd[tid] - v;
    rowptr[i] = excl;
    cursor[i] = excl;
  }
}

__global__ __launch_bounds__(256) void k_fill(const int* __restrict__ src,
                                              const int* __restrict__ dst,
                                              int* __restrict__ cursor,
                                              int* __restrict__ eid) {
  int i0 = blockIdx.x * blockDim.x + threadIdx.x;
  int stride = gridDim.x * blockDim.x;
  for (int e = i0; e < NE; e += stride) {
    int pos = atomicAdd(&cursor[dst[e]], 1);
    eid[pos] = src[e];
  }
}

// ------- dual proj layer 1: P = x@Wl.T ; Q = x@Wr.T + bl  (128 -> 64) -------
__global__ __launch_bounds__(256) void k_dual_proj1(
    const float* __restrict__ X, const float* __restrict__ Wl,
    const float* __restrict__ Wr, const float* __restrict__ bl,
    float* __restrict__ P, float* __restrict__ Q) {
  __shared__ float swl[NF * LDSP1];
  __shared__ float swr[NF * LDSP1];
  int tid = threadIdx.x;
  for (int i = tid; i < NF * NH; i += 256) {
    int o = i >> 7, k = i & 127;
    swl[k * LDSP1 + o] = Wl[i];  // write banks stride 1 mod 32: conflict-free
    swr[k * LDSP1 + o] = Wr[i];
  }
  __syncthreads();
  int lane = tid & 63;
  int wave = blockIdx.x * 4 + (tid >> 6);
  int nw = gridDim.x * 4;
  float blv = bl[lane];
  const int ngroups = NN / 8;  // 6250 exactly
  for (int g = wave; g < ngroups; g += nw) {
    int n0 = g * 8;
    const float4* xr = (const float4*)(X + (size_t)n0 * NF);
    float accP[8], accQ[8];
#pragma unroll
    for (int m = 0; m < 8; ++m) { accP[m] = 0.f; accQ[m] = 0.f; }
#pragma unroll 4
    for (int kk = 0; kk < 32; ++kk) {
      const float* wl4 = &swl[(kk * 4) * LDSP1 + lane];
      const float* wr4 = &swr[(kk * 4) * LDSP1 + lane];
      float l0 = wl4[0], l1 = wl4[LDSP1], l2 = wl4[2 * LDSP1], l3 = wl4[3 * LDSP1];
      float r0 = wr4[0], r1 = wr4[LDSP1], r2 = wr4[2 * LDSP1], r3 = wr4[3 * LDSP1];
#pragma unroll
      for (int m = 0; m < 8; ++m) {
        float4 v = xr[m * 32 + kk];  // wave-uniform broadcast
        accP[m] += v.x * l0 + v.y * l1 + v.z * l2 + v.w * l3;
        accQ[m] += v.x * r0 + v.y * r1 + v.z * r2 + v.w * r3;
      }
    }
#pragma unroll
    for (int m = 0; m < 8; ++m) {
      P[(size_t)(n0 + m) * NH + lane] = accP[m];
      Q[(size_t)(n0 + m) * NH + lane] = accQ[m] + blv;
    }
  }
}

// ------- dual proj layer 2: P2 = h@Wl2.T ; Q2 = h@Wr2.T + bl2  (64 -> 40) ----
__global__ __launch_bounds__(256) void k_dual_proj2(
    const float* __restrict__ H, const float* __restrict__ Wl,
    const float* __restrict__ Wr, const float* __restrict__ bl,
    float* __restrict__ P2, float* __restrict__ Q2) {
  __shared__ float swl[NH * LDSP2 + 64];  // +64 pad: lanes 40..63 read OOB-safe
  __shared__ float swr[NH * LDSP2 + 64];
  int tid = threadIdx.x;
  for (int i = tid; i < NC * NH; i += 256) {
    int j = i >> 6, k = i & 63;
    swl[k * LDSP2 + j] = Wl[i];
    swr[k * LDSP2 + j] = Wr[i];
  }
  __syncthreads();
  int lane = tid & 63;
  int wave = blockIdx.x * 4 + (tid >> 6);
  int nw = gridDim.x * 4;
  float blv = (lane < NC) ? bl[lane] : 0.f;
  const int ngroups = NN / 8;
  for (int g = wave; g < ngroups; g += nw) {
    int n0 = g * 8;
    const float4* hr = (const float4*)(H + (size_t)n0 * NH);
    float accP[8], accQ[8];
#pragma unroll
    for (int m = 0; m < 8; ++m) { accP[m] = 0.f; accQ[m] = 0.f; }
#pragma unroll 4
    for (int kk = 0; kk < 16; ++kk) {
      const float* wl4 = &swl[(kk * 4) * LDSP2 + lane];
      const float* wr4 = &swr[(kk * 4) * LDSP2 + lane];
      float l0 = wl4[0], l1 = wl4[LDSP2], l2 = wl4[2 * LDSP2], l3 = wl4[3 * LDSP2];
      float r0 = wr4[0], r1 = wr4[LDSP2], r2 = wr4[2 * LDSP2], r3 = wr4[3 * LDSP2];
#pragma unroll
      for (int m = 0; m < 8; ++m) {
        float4 v = hr[m * 16 + kk];
        accP[m] += v.x * l0 + v.y * l1 + v.z * l2 + v.w * l3;
        accQ[m] += v.x * r0 + v.y * r1 + v.z * r2 + v.w * r3;
      }
    }
    if (lane < NC) {
#pragma unroll
      for (int m = 0; m < 8; ++m) {
        P2[(size_t)(n0 + m) * NC + lane] = accP[m];
        Q2[(size_t)(n0 + m) * NC + lane] = accQ[m] + blv;
      }
    }
  }
}

// ------- gather64: h = sigmoid(q1 + mean_{src->n} p1[src]) -------
__global__ __launch_bounds__(256) void k_gather64(
    const float* __restrict__ P, const float* __restrict__ Q,
    const int* __restrict__ rowptr, const int* __restrict__ deg,
    const int* __restrict__ eid, float* __restrict__ H) {
  int lane = threadIdx.x & 63;
  int wave = blockIdx.x * 4 + (threadIdx.x >> 6);
  int nw = gridDim.x * 4;
  for (int n = wave; n < NN; n += nw) {
    int r0 = rowptr[n], dg = deg[n];
    float a0 = 0.f, a1 = 0.f;
    for (int base = 0; base < dg; base += 64) {
      int e = dg - base;
      if (e > 64) e = 64;
      int myeid = (lane < e) ? eid[r0 + base + lane] : 0;
      int j = 0;
      for (; j + 4 <= e; j += 4) {
        int s0 = __shfl(myeid, j);
        int s1 = __shfl(myeid, j + 1);
        int s2 = __shfl(myeid, j + 2);
        int s3 = __shfl(myeid, j + 3);
        float v0 = P[(size_t)s0 * NH + lane];
        float v1 = P[(size_t)s1 * NH + lane];
        float v2 = P[(size_t)s2 * NH + lane];
        float v3 = P[(size_t)s3 * NH + lane];
        a0 += v0 + v2;
        a1 += v1 + v3;
      }
      for (; j < e; ++j) a0 += P[(size_t)__shfl(myeid, j) * NH + lane];
    }
    float inv = 1.0f / (float)(dg > 0 ? dg : 1);
    float val = (a0 + a1) * inv + Q[(size_t)n * NH + lane];
    H[(size_t)n * NH + lane] = 1.0f / (1.0f + __expf(-val));
  }
}

// ------- gather40: out = q2 + mean_{src->n} p2[src] -------
__global__ __launch_bounds__(256) void k_gather40(
    const float* __restrict__ P2, const float* __restrict__ Q2,
    const int* __restrict__ rowptr, const int* __restrict__ deg,
    const int* __restrict__ eid, float* __restrict__ Out) {
  int lane = threadIdx.x & 63;
  int wave = blockIdx.x * 4 + (threadIdx.x >> 6);
  int nw = gridDim.x * 4;
  for (int n = wave; n < NN; n += nw) {
    int r0 = rowptr[n], dg = deg[n];
    float a0 = 0.f, a1 = 0.f;
    for (int base = 0; base < dg; base += 64) {
      int e = dg - base;
      if (e > 64) e = 64;
      int myeid = (lane < e) ? eid[r0 + base + lane] : 0;
      int j = 0;
      for (; j + 4 <= e; j += 4) {
        int s0 = __shfl(myeid, j);
        int s1 = __shfl(myeid, j + 1);
        int s2 = __shfl(myeid, j + 2);
        int s3 = __shfl(myeid, j + 3);
        if (lane < NC) {
          float v0 = P2[(size_t)s0 * NC + lane];
          float v1 = P2[(size_t)s1 * NC + lane];
          float v2 = P2[(size_t)s2 * NC + lane];
          float v3 = P2[(size_t)s3 * NC + lane];
          a0 += v0 + v2;
          a1 += v1 + v3;
        }
      }
      for (; j < e; ++j) {
        int s0 = __shfl(myeid, j);
        if (lane < NC) a0 += P2[(size_t)s0 * NC + lane];
      }
    }
    if (lane < NC) {
      float inv = 1.0f / (float)(dg > 0 ? dg : 1);
      Out[(size_t)n * NC + lane] = (a0 + a1) * inv + Q2[(size_t)n * NC + lane];
    }
  }
}

extern "C" void kernel_launch(void* const* d_in, const int* in_sizes, int n_in,
                              void* d_out, int out_size, void* d_ws,
                              size_t ws_size, hipStream_t stream) {
  const float* x = (const float*)d_in[0];
  const int* ei = (const int*)d_in[1];
  const float* Wl1 = (const float*)d_in[2];
  const float* bl1 = (const float*)d_in[3];
  const float* Wr1 = (const float*)d_in[4];
  const float* Wl2 = (const float*)d_in[5];
  const float* bl2 = (const float*)d_in[6];
  const float* Wr2 = (const float*)d_in[7];
  float* out = (float*)d_out;

  const int* src = ei;       // edge_index[0]
  const int* dst = ei + NE;  // edge_index[1]

  // workspace layout (floats)
  float* fws = (float*)d_ws;
  float* p1 = fws;                          // [NN*64]
  float* q1 = p1 + (size_t)NN * NH;         // [NN*64]
  float* h = q1 + (size_t)NN * NH;          // [NN*64]
  // p1/q1 dead after gather64 -> reuse for layer 2
  float* p2 = fws;                          // [NN*40]
  float* q2 = fws + (size_t)NN * NC;        // [NN*40]
  int* deg = (int*)(h + (size_t)NN * NH);   // [NN] (zeroed)
  int* rowptr = deg + NN;                   // [NN]
  int* cursor = rowptr + NN;                // [NN]
  int* blocksum = cursor + NN;              // [128]
  int* blockoff = blocksum + 128;           // [128]
  int* eid = blockoff + 128;                // [NE]

  hipMemsetAsync(deg, 0, NN * sizeof(int), stream);

  // CSR build
  k_hist<<<1024, 256, 0, stream>>>(dst, deg);
  k_scan1<<<SCAN_NBLK, SCAN_TPB, 0, stream>>>(deg, blocksum);
  k_scan2<<<1, 128, 0, stream>>>(blocksum, blockoff);
  k_scan3<<<SCAN_NBLK, SCAN_TPB, 0, stream>>>(deg, blockoff, rowptr, cursor);
  k_fill<<<1024, 256, 0, stream>>>(src, dst, cursor, eid);

  // layer 1
  k_dual_proj1<<<512, 256, 0, stream>>>(x, Wl1, Wr1, bl1, p1, q1);
  k_gather64<<<2048, 256, 0, stream>>>(p1, q1, rowptr, deg, eid, h);

  // layer 2
  k_dual_proj2<<<512, 256, 0, stream>>>(h, Wl2, Wr2, bl2, p2, q2);
  k_gather40<<<2048, 256, 0, stream>>>(p2, q2, rowptr, deg, eid, out);
}